// Round 11
// baseline (309.513 us; speedup 1.0000x reference)
//
#include <hip/hip_runtime.h>
#include <hip/hip_bf16.h>
#include <math.h>

#define NN   29040
#define NLAT 121
#define NLON 240
#define HD   128
#define LVN  11
#define EE   464640

typedef __attribute__((ext_vector_type(8))) short short8;
typedef __attribute__((ext_vector_type(16))) float f16v;

// packed-weight offsets (in shorts) inside wp buffer
#define OFF_WE1 0          // 20 kf x 4 nf  = 80 frags (1 KB each)
#define OFF_WE2 40960      // 8 x 4 = 32
#define OFF_WC1 57344      // 8 x 4 = 32
#define OFF_WCL 73728      // 8 x 1 = 8
#define OFF_WN1 77824      // 24 x 4 = 96
#define OFF_WN2 126976     // 8 x 4 = 32
#define WP_SHORTS 143360

__device__ inline short f2b(float x) {
    union { __hip_bfloat16 b; short s; } v;
    v.b = __float2bfloat16(x);
    return v.s;
}
__device__ inline float b2f(unsigned short b) {
    union { unsigned u; float f; } v; v.u = ((unsigned)b) << 16;
    return v.f;
}

// ================= fused setup: hist | h-cast | uv-prep | weight-pack =================
#define SB_HIST  1815
#define SB_HCAST 1815
#define SB_UV    114
#define SB_WP    70

__global__ __launch_bounds__(256)
void setup_kernel(const int* __restrict__ eidx, int* __restrict__ cnt,
                  const float* __restrict__ h, short* __restrict__ hb,
                  const float* __restrict__ u, const float* __restrict__ v,
                  float* __restrict__ uvrec,
                  const float* __restrict__ We1, const float* __restrict__ We2,
                  const float* __restrict__ Wc1, const float* __restrict__ Wcl,
                  const float* __restrict__ Wn1, const float* __restrict__ Wn2,
                  short* __restrict__ wp)
{
    const int b = blockIdx.x, tid = threadIdx.x;
    if (b < SB_HIST) {
        int e = b * 256 + tid;
        atomicAdd(&cnt[eidx[e]], 1);
        return;
    }
    if (b < SB_HIST + SB_HCAST) {
        int idx = (b - SB_HIST) * 256 + tid;          // 8 elems each
        const float4* hf = (const float4*)h;
        float4 a = hf[idx * 2], c = hf[idx * 2 + 1];
        short8 o;
        o[0] = f2b(a.x); o[1] = f2b(a.y); o[2] = f2b(a.z); o[3] = f2b(a.w);
        o[4] = f2b(c.x); o[5] = f2b(c.y); o[6] = f2b(c.z); o[7] = f2b(c.w);
        ((short8*)hb)[idx] = o;
        return;
    }
    if (b < SB_HIST + SB_HCAST + SB_UV) {
        int n = (b - SB_HIST - SB_HCAST) * 256 + tid;
        if (n >= NN) return;
        float* r = uvrec + (size_t)n * 36;
        float un = 0.f, vn = 0.f;
#pragma unroll
        for (int l = 0; l < LVN; ++l) {
            float uu = u[n * LVN + l], vv = v[n * LVN + l];
            float s = sqrtf(uu * uu + vv * vv);
            r[l]      = uu / s;
            r[11 + l] = vv / s;
            r[22 + l] = s;
            un += uu * uu; vn += vv * vv;
        }
        r[33] = sqrtf(un);
        r[34] = sqrtf(vn);
        r[35] = 0.f;
        return;
    }
    // ---- weight pack for 32x32x16 MFMA B-fragments ----
    // lane l, elem i -> k = kf*16 + 8*(l>>5) + i ; n = nf*32 + (l&31)
    {
        int fg = (b - SB_HIST - SB_HCAST - SB_UV) * 4 + (tid >> 6);   // 0..279
        const int l = tid & 63;
        int kind, f, base;
        if (fg < 80)       { kind = 0; f = fg;       base = OFF_WE1; }   // 20x4
        else if (fg < 112) { kind = 1; f = fg - 80;  base = OFF_WE2; }   // 8x4
        else if (fg < 144) { kind = 2; f = fg - 112; base = OFF_WC1; }   // 8x4
        else if (fg < 152) { kind = 3; f = fg - 144; base = OFF_WCL; }   // 8x1
        else if (fg < 248) { kind = 4; f = fg - 152; base = OFF_WN1; }   // 24x4
        else               { kind = 5; f = fg - 248; base = OFF_WN2; }   // 8x4
        const int nfw = (kind == 3) ? 1 : 4;
        const int kf = f / nfw, nf = f % nfw;
        short* dst = wp + base + (size_t)f * 512 + l * 8;
        for (int i = 0; i < 8; ++i) {
            int k = kf * 16 + ((l >> 5) << 3) + i;
            int n = nf * 32 + (l & 31);
            float val = 0.f;
            if (kind == 0) {
                int r = (k < 33) ? (256 + k) : (k == 33 ? 289 : (k < 64 ? -1 : k - 64));
                if (r >= 0) val = We1[r * HD + n];
            } else if (kind == 1) val = We2[k * HD + n];
            else if (kind == 2)  val = Wc1[k * HD + n];
            else if (kind == 3)  { if (n < 22) val = Wcl[k * 22 + n]; }
            else if (kind == 4)  val = Wn1[k * HD + n];
            else                 val = Wn2[k * HD + n];
            dst[i] = f2b(val);
        }
    }
}

// ================= CSR scan + scatter =================
__global__ __launch_bounds__(1024)
void scan_kernel(const int* __restrict__ cnt, int* __restrict__ off)
{
    __shared__ int part[1024];
    const int tid = threadIdx.x;
    const int CH = 29;
    int lo = tid * CH, hi = min(lo + CH, NN);
    int s = 0;
    for (int i = lo; i < hi; ++i) s += cnt[i];
    part[tid] = s;
    __syncthreads();
    for (int d = 1; d < 1024; d <<= 1) {
        int vv = (tid >= d) ? part[tid - d] : 0;
        __syncthreads();
        part[tid] += vv;
        __syncthreads();
    }
    int run = (tid == 0) ? 0 : part[tid - 1];
    for (int i = lo; i < hi; ++i) { off[i] = run; run += cnt[i]; }
    if (tid == 1023) off[NN] = run;
}

__global__ __launch_bounds__(256)
void scatter_kernel(const int* __restrict__ eidx, const int* __restrict__ off,
                    int* __restrict__ cur, int* __restrict__ csr)
{
    int e = blockIdx.x * 256 + threadIdx.x;
    if (e >= EE) return;
    int row = eidx[e];
    int p = atomicAdd(&cur[row], 1);
    csr[off[row] + p] = e;
}

// ================= 32x32x16 GEMM helpers (2 M-frags per wave) =================
// C layout [HW-verified m74/m101]: col = lane&31, row = (reg&3)+8*(reg>>2)+4*(lane>>5)

// GEMM from a T1-style LDS tile (256B rows, swizzled), K = 128, 2 M-frags.
// acc flat [m*NJ + j].
template<int NFL, int NJ>
__device__ inline void gemm_t1(const short* T1, const short* Wp, int nf0,
                               const float* bias, f16v* acc,
                               int row0, int colbase, int r31, int kh, int lane)
{
    const int sw = (row0 & 7) << 4;
    const char* a0p = (const char*)T1 + row0 * 256;
    const char* a1p = a0p + 32 * 256;
#pragma unroll
    for (int m = 0; m < 2; ++m)
#pragma unroll
        for (int j = 0; j < NJ; ++j) {
            float bv = bias ? bias[colbase + j * 32 + r31] : 0.f;
#pragma unroll
            for (int q = 0; q < 16; ++q) acc[m * NJ + j][q] = bv;
        }
#pragma unroll
    for (int kf = 0; kf < 8; ++kf) {
        short8 a0 = *(const short8*)(a0p + ((kf * 32 + 16 * kh) ^ sw));
        short8 a1 = *(const short8*)(a1p + ((kf * 32 + 16 * kh) ^ sw));
#pragma unroll
        for (int j = 0; j < NJ; ++j) {
            short8 b = *(const short8*)(Wp + (size_t)(kf * NFL + nf0 + j) * 512 + lane * 8);
            acc[0 * NJ + j] = __builtin_amdgcn_mfma_f32_32x32x16_bf16(a0, b, acc[0 * NJ + j], 0, 0, 0);
            acc[1 * NJ + j] = __builtin_amdgcn_mfma_f32_32x32x16_bf16(a1, b, acc[1 * NJ + j], 0, 0, 0);
        }
    }
}

// store 2m x NJ C-frags (optional relu) into 256B-row swizzled bf16 tile
template<int NJ>
__device__ inline void store_mj(short* tile, const f16v* acc, int rwbase, int colbase,
                                int r31, int kh, bool relu)
{
#pragma unroll
    for (int m = 0; m < 2; ++m)
#pragma unroll
        for (int j = 0; j < NJ; ++j)
#pragma unroll
            for (int reg = 0; reg < 16; ++reg) {
                int row = rwbase + 32 * m + (reg & 3) + 8 * (reg >> 2) + 4 * kh;
                int cb2 = (colbase + j * 32 + r31) * 2;
                float vv = acc[m * NJ + j][reg];
                if (relu) vv = fmaxf(vv, 0.f);
                *(short*)((char*)tile + row * 256 + (cb2 ^ ((row & 7) << 4))) = f2b(vv);
            }
}

// ================= edge kernel: 128-edge tiles, 4 waves of 64x64 =================
// Wave w: rw=w>>1 (rows 64rw..+63 = 2 M-frags), cg=w&1 (cols 64cg..+63 = 2 B-frags).
// Each 1KB B-frag load feeds 2 MFMAs / 64 edges -> per-edge weight-L1 traffic
// 4.75 -> ~2.4 KB (the r9/r10-confirmed bottleneck). acc = 64 AGPRs; (256,3)
// keeps the VGPR budget at ~168 so the allocator cannot spill it (r5/r6 lesson).
__global__ __launch_bounds__(256, 3)
void edge_mfma(const short* __restrict__ hb, const float* __restrict__ uvrec,
               const float* __restrict__ ea,
               const float* __restrict__ be1, const float* __restrict__ be2,
               const float* __restrict__ bc1,
               const short* __restrict__ wp,
               const int* __restrict__ eidx, const int* __restrict__ csr,
               float* __restrict__ agg, float* __restrict__ aggu,
               float* __restrict__ aggv)
{
    __shared__ short Twd[128 * 64];    // 16 KB wd tile (128B rows); later O22 f32 overlay
    __shared__ short T1[128 * 128];    // 32 KB tile (256B rows)
    __shared__ int   rows_s[128];
    __shared__ float radu_s[128], radv_s[128];

    const int tid = threadIdx.x, lane = tid & 63, w = tid >> 6;
    const int rw = w >> 1, cg = w & 1;
    const int e0 = blockIdx.x * 128;
    const int r31 = lane & 31, kh = lane >> 5;
    const int row0 = rw * 64 + r31;                // M-frag 0 row
    const int sw = (row0 & 7) << 4;                // (row0+32)&7 == row0&7
    const int colbase = cg * 64;

    // ---- own-row index chains + gather pointers for BOTH edges of this lane ----
    int ea1 = csr[e0 + row0], eb1 = csr[e0 + row0 + 32];
    int rowa = eidx[ea1], cola = eidx[EE + ea1];
    int rowb = eidx[eb1], colb = eidx[EE + eb1];
    const short* hr0 = hb + (size_t)rowa * HD + 8 * kh;
    const short* hc0 = hb + (size_t)cola * HD + 8 * kh;
    const short* hr1 = hb + (size_t)rowb * HD + 8 * kh;
    const short* hc1 = hb + (size_t)colb * HD + 8 * kh;

    // ---- wd tile build (2 threads per row; wave-synchronous zero-then-store) ----
    {
        const int m2 = tid >> 1, q = tid & 1;
        const int sw2 = (m2 & 7) << 4;
        int e2 = csr[e0 + m2];
        int row2 = eidx[e2], col2 = eidx[EE + e2];
        const float* rc = uvrec + (size_t)col2 * 36;
        const float* rr = uvrec + (size_t)row2 * 36;
        char* arow = (char*)(Twd + m2 * 64);
        short8 z = {0, 0, 0, 0, 0, 0, 0, 0};
        *(short8*)(arow + q * 64) = z;
        *(short8*)(arow + q * 64 + 16) = z;
        *(short8*)(arow + q * 64 + 32) = z;
        *(short8*)(arow + q * 64 + 48) = z;
        for (int l = q; l < LVN; l += 2) {
            float rel = rc[l] * rr[l] + rc[11 + l] * rr[11 + l];
            *(short*)(arow + ((2 * l) ^ sw2))        = f2b(rel);
            *(short*)(arow + ((2 * (11 + l)) ^ sw2)) = f2b(rc[22 + l]);
            *(short*)(arow + ((2 * (22 + l)) ^ sw2)) = f2b(rr[22 + l]);
        }
        if (q == 0) {
            rows_s[m2] = row2; radu_s[m2] = rc[33]; radv_s[m2] = rc[34];
            *(short*)(arow + ((2 * 33) ^ sw2)) = f2b(ea[e2]);
        }
    }
    __syncthreads();   // B1: Twd/rows_s/rad visible

    // ==== edge MLP layer 1: A = [wd(k 0..63) | h_row(64..191) | h_col(192..319)] ====
    f16v acc[4];   // [m*2 + j]
#pragma unroll
    for (int m = 0; m < 2; ++m)
#pragma unroll
        for (int j = 0; j < 2; ++j) {
            float bv = be1[colbase + j * 32 + r31];
#pragma unroll
            for (int q = 0; q < 16; ++q) acc[m * 2 + j][q] = bv;
        }
    {
        const char* awd0 = (const char*)Twd + row0 * 128;
        const char* awd1 = awd0 + 32 * 128;
#pragma unroll
        for (int kf = 0; kf < 4; ++kf) {
            short8 a0 = *(const short8*)(awd0 + ((kf * 32 + 16 * kh) ^ sw));
            short8 a1 = *(const short8*)(awd1 + ((kf * 32 + 16 * kh) ^ sw));
#pragma unroll
            for (int j = 0; j < 2; ++j) {
                short8 b = *(const short8*)(wp + OFF_WE1 + (size_t)(kf * 4 + cg * 2 + j) * 512 + lane * 8);
                acc[j]     = __builtin_amdgcn_mfma_f32_32x32x16_bf16(a0, b, acc[j], 0, 0, 0);
                acc[2 + j] = __builtin_amdgcn_mfma_f32_32x32x16_bf16(a1, b, acc[2 + j], 0, 0, 0);
            }
        }
#pragma unroll
        for (int s = 0; s < 8; ++s) {
            short8 a0 = *(const short8*)(hr0 + s * 16);
            short8 a1 = *(const short8*)(hr1 + s * 16);
#pragma unroll
            for (int j = 0; j < 2; ++j) {
                short8 b = *(const short8*)(wp + OFF_WE1 + (size_t)((s + 4) * 4 + cg * 2 + j) * 512 + lane * 8);
                acc[j]     = __builtin_amdgcn_mfma_f32_32x32x16_bf16(a0, b, acc[j], 0, 0, 0);
                acc[2 + j] = __builtin_amdgcn_mfma_f32_32x32x16_bf16(a1, b, acc[2 + j], 0, 0, 0);
            }
        }
#pragma unroll
        for (int s = 0; s < 8; ++s) {
            short8 a0 = *(const short8*)(hc0 + s * 16);
            short8 a1 = *(const short8*)(hc1 + s * 16);
#pragma unroll
            for (int j = 0; j < 2; ++j) {
                short8 b = *(const short8*)(wp + OFF_WE1 + (size_t)((s + 12) * 4 + cg * 2 + j) * 512 + lane * 8);
                acc[j]     = __builtin_amdgcn_mfma_f32_32x32x16_bf16(a0, b, acc[j], 0, 0, 0);
                acc[2 + j] = __builtin_amdgcn_mfma_f32_32x32x16_bf16(a1, b, acc[2 + j], 0, 0, 0);
            }
        }
    }
    store_mj<2>(T1, acc, rw * 64, colbase, r31, kh, true);    // Y1
    __syncthreads();   // B2: Y1 complete (L2's K spans both cg halves)

    // ==== edge MLP layer 2 ====
    gemm_t1<4, 2>(T1, wp + OFF_WE2, cg * 2, be2, acc, row0, colbase, r31, kh, lane);
    __syncthreads();   // B2.5: Y1 reads done before EF overwrite
    store_mj<2>(T1, acc, rw * 64, colbase, r31, kh, true);    // EF
    __syncthreads();   // B3: EF complete

    // ==== coord MLP layer 1 (reads EF) ====
    gemm_t1<4, 2>(T1, wp + OFF_WC1, cg * 2, bc1, acc, row0, colbase, r31, kh, lane);

    // ==== agg: segmented reduce over sorted rows (32-row chains, 2 per thread) ====
    {
        const int col = tid & 127;
        for (int cc = (tid >> 7); cc < 4; cc += 2) {
            const int m0 = cc * 32;
            int curr = rows_s[m0]; float s = 0.f;
            for (int m = m0; m < m0 + 32; ++m) {
                int r = rows_s[m];
                float vv = b2f(*(const unsigned short*)((const char*)T1 + m * 256 + ((col * 2) ^ ((m & 7) << 4))));
                if (r != curr) { atomicAdd(&agg[(size_t)curr * HD + col], s); s = 0.f; curr = r; }
                s += vv;
            }
            atomicAdd(&agg[(size_t)curr * HD + col], s);
        }
    }
    __syncthreads();   // B4: EF reads (C1 gemm + reduce) done
    store_mj<2>(T1, acc, rw * 64, colbase, r31, kh, true);    // C1
    __syncthreads();   // B5: C1 complete

    // ==== coord final layer (cg=0 waves; N=22 in one 32-col frag) ====
    if (cg == 0) {
        f16v acc2[2];
        gemm_t1<1, 1>(T1, wp + OFF_WCL, 0, (const float*)nullptr, acc2, row0, 0, r31, kh, lane);
        float* O22 = (float*)Twd;               // 128x32 f32 overlay (wd dead)
#pragma unroll
        for (int m = 0; m < 2; ++m)
#pragma unroll
            for (int reg = 0; reg < 16; ++reg) {
                int row = rw * 64 + 32 * m + (reg & 3) + 8 * (reg >> 2) + 4 * kh;
                O22[row * 32 + r31] = acc2[m][reg];
            }
    }
    __syncthreads();   // B6: O22 visible

    // ==== wind: segmented reduce (8 chunks x 16 rows) ====
    {
        const int c = tid & 31, ch = tid >> 5;
        if (c < 22) {
            const bool isU = c < LVN;
            const int lvl = isU ? c : c - LVN;
            float* dst = isU ? aggu : aggv;
            const float* radp = isU ? radu_s : radv_s;
            const float* O22 = (const float*)Twd;
            const int m0 = ch * 16;
            int curr = rows_s[m0]; float s = 0.f;
            for (int m = m0; m < m0 + 16; ++m) {
                int r = rows_s[m];
                float vv = O22[m * 32 + c] * radp[m];
                if (r != curr) { atomicAdd(&dst[(size_t)curr * LVN + lvl], s); s = 0.f; curr = r; }
                s += vv;
            }
            atomicAdd(&dst[(size_t)curr * LVN + lvl], s);
        }
    }
}

// ================= post: lat-band mean | wind finalize =================
__global__ __launch_bounds__(256)
void post_kernel(const float* __restrict__ agg, short* __restrict__ latb,
                 float* __restrict__ aggu, float* __restrict__ aggv,
                 const int* __restrict__ off)
{
    const int b = blockIdx.x, tid = threadIdx.x;
    if (b < NLAT) {
        __shared__ float part[256];
        const int j = tid & 127, half = tid >> 7;
        float s = 0.f;
        for (int lon = half * 120; lon < (half + 1) * 120; ++lon)
            s += agg[((size_t)b * NLON + lon) * HD + j];
        part[tid] = s;
        __syncthreads();
        if (tid < 128)
            latb[(size_t)b * HD + tid] = f2b((part[tid] + part[128 + tid]) * (1.0f / NLON));
        return;
    }
    int tt = (b - NLAT) * 256 + tid;
    if (tt >= NN * LVN) return;
    int n = tt / LVN;
    float c = fmaxf((float)(off[n + 1] - off[n]), 1.f);
    float xu = aggu[tt] / c, xv = aggv[tt] / c;
    aggu[tt] = fminf(fmaxf(xu, -100.f), 100.f);
    aggv[tt] = fminf(fmaxf(xv, -100.f), 100.f);
}

// ================= node kernel: 128-node tiles, 8 waves, 32x32x16 =================
__global__ __launch_bounds__(512, 4)
void node_mfma(const short* __restrict__ hb, const float* __restrict__ h,
               const short* __restrict__ latb,
               const float* __restrict__ bn1, const float* __restrict__ bn2,
               const short* __restrict__ wp, float* __restrict__ out)
{
    __shared__ short T1[128 * 128];    // 32 KB
    const int tid = threadIdx.x, lane = tid & 63, w = tid >> 6;   // 8 waves
    const int rg = w >> 1, cg = w & 1;                             // rg 0..3
    const int r31 = lane & 31, kh = lane >> 5;
    const int mrow = rg * 32 + r31;                                // 0..127
    const int sw = (mrow & 7) << 4;
    const int colbase = cg * 64;
    const int n0 = blockIdx.x * 128;
    const int n = n0 + mrow;
    const int nc = (n < NN) ? n : (NN - 1);
    const short* hp = hb + (size_t)nc * HD + 8 * kh;
    const float* ap = out + (size_t)nc * HD + 8 * kh;   // agg lives in out region
    const short* lp = latb + (size_t)(nc / NLON) * HD + 8 * kh;

    f16v acc[2];
#pragma unroll
    for (int j = 0; j < 2; ++j) {
        float bv = bn1[colbase + j * 32 + r31];
#pragma unroll
        for (int q = 0; q < 16; ++q) acc[j][q] = bv;
    }
    // h part (k 0..127)
#pragma unroll
    for (int s = 0; s < 8; ++s) {
        short8 a = *(const short8*)(hp + s * 16);
#pragma unroll
        for (int j = 0; j < 2; ++j) {
            short8 bfr = *(const short8*)(wp + OFF_WN1 + (size_t)(s * 4 + cg * 2 + j) * 512 + lane * 8);
            acc[j] = __builtin_amdgcn_mfma_f32_32x32x16_bf16(a, bfr, acc[j], 0, 0, 0);
        }
    }
    // agg part (k 128..255), f32 -> bf16 in reg
#pragma unroll
    for (int s = 0; s < 8; ++s) {
        short8 a;
#pragma unroll
        for (int q = 0; q < 8; ++q) a[q] = f2b(ap[s * 16 + q]);
#pragma unroll
        for (int j = 0; j < 2; ++j) {
            short8 bfr = *(const short8*)(wp + OFF_WN1 + (size_t)((s + 8) * 4 + cg * 2 + j) * 512 + lane * 8);
            acc[j] = __builtin_amdgcn_mfma_f32_32x32x16_bf16(a, bfr, acc[j], 0, 0, 0);
        }
    }
    // lat part (k 256..383)
#pragma unroll
    for (int s = 0; s < 8; ++s) {
        short8 a = *(const short8*)(lp + s * 16);
#pragma unroll
        for (int j = 0; j < 2; ++j) {
            short8 bfr = *(const short8*)(wp + OFF_WN1 + (size_t)((s + 16) * 4 + cg * 2 + j) * 512 + lane * 8);
            acc[j] = __builtin_amdgcn_mfma_f32_32x32x16_bf16(a, bfr, acc[j], 0, 0, 0);
        }
    }
    // store (relu) then layer 2
    {
#pragma unroll
        for (int j = 0; j < 2; ++j)
#pragma unroll
            for (int reg = 0; reg < 16; ++reg) {
                int row = rg * 32 + (reg & 3) + 8 * (reg >> 2) + 4 * kh;
                int cb2 = (colbase + j * 32 + r31) * 2;
                *(short*)((char*)T1 + row * 256 + (cb2 ^ ((row & 7) << 4))) = f2b(fmaxf(acc[j][reg], 0.f));
            }
    }
    __syncthreads();
    {
        const char* arow = (const char*)T1 + mrow * 256;
#pragma unroll
        for (int j = 0; j < 2; ++j) {
            float bv = bn2[colbase + j * 32 + r31];
#pragma unroll
            for (int q = 0; q < 16; ++q) acc[j][q] = bv;
        }
#pragma unroll
        for (int kf = 0; kf < 8; ++kf) {
            short8 a = *(const short8*)(arow + ((kf * 32 + 16 * kh) ^ sw));
#pragma unroll
            for (int j = 0; j < 2; ++j) {
                short8 bfr = *(const short8*)(wp + OFF_WN2 + (size_t)(kf * 4 + cg * 2 + j) * 512 + lane * 8);
                acc[j] = __builtin_amdgcn_mfma_f32_32x32x16_bf16(a, bfr, acc[j], 0, 0, 0);
            }
        }
    }
    // out = acc + h (residual)
#pragma unroll
    for (int j = 0; j < 2; ++j)
#pragma unroll
        for (int reg = 0; reg < 16; ++reg) {
            int row = rg * 32 + (reg & 3) + 8 * (reg >> 2) + 4 * kh;
            int gn = n0 + row;
            if (gn < NN) {
                int col = colbase + j * 32 + r31;
                out[(size_t)gn * HD + col] = acc[j][reg] + h[(size_t)gn * HD + col];
            }
        }
}

extern "C" void kernel_launch(void* const* d_in, const int* in_sizes, int n_in,
                              void* d_out, int out_size, void* d_ws, size_t ws_size,
                              hipStream_t stream)
{
    const float* h   = (const float*)d_in[0];
    const float* u   = (const float*)d_in[1];
    const float* v   = (const float*)d_in[2];
    const float* ea  = (const float*)d_in[3];
    const float* We1 = (const float*)d_in[4];
    const float* be1 = (const float*)d_in[5];
    const float* We2 = (const float*)d_in[6];
    const float* be2 = (const float*)d_in[7];
    const float* Wn1 = (const float*)d_in[8];
    const float* bn1 = (const float*)d_in[9];
    const float* Wn2 = (const float*)d_in[10];
    const float* bn2 = (const float*)d_in[11];
    const float* Wc1 = (const float*)d_in[12];
    const float* bc1 = (const float*)d_in[13];
    const float* Wcl = (const float*)d_in[14];
    const int*   eidx = (const int*)d_in[15];

    float* out  = (float*)d_out;
    float* agg  = out;                       // [NN,HD]: agg accum, then h_out
    float* aggu = out + (size_t)NN * HD;
    float* aggv = aggu + (size_t)NN * LVN;

    // ---- workspace layout (no overlaps) ----
    char* p = (char*)d_ws;
    short* wp  = (short*)p;                  p += (size_t)WP_SHORTS * 2;
    int*   off = (int*)p;                    p += (size_t)(NN + 1) * 4;
    int*   csr = (int*)p;                    p += (size_t)EE * 4;
    p = (char*)(((size_t)p + 15) & ~(size_t)15);
    short* hb  = (short*)p;                  p += (size_t)NN * HD * 2;
    float* uvr = (float*)p;                  p += (size_t)NN * 36 * 4;
    short* latb = (short*)p;                 p += (size_t)NLAT * HD * 2;
    p = (char*)(((size_t)p + 15) & ~(size_t)15);
    int*   cnt = (int*)p;                    p += (size_t)NN * 4;
    int*   cur = (int*)p;

    hipMemsetAsync(d_out, 0, (size_t)out_size * sizeof(float), stream);
    hipMemsetAsync(cnt, 0, (size_t)2 * NN * sizeof(int), stream);

    setup_kernel<<<SB_HIST + SB_HCAST + SB_UV + SB_WP, 256, 0, stream>>>(
        eidx, cnt, h, hb, u, v, uvr, We1, We2, Wc1, Wcl, Wn1, Wn2, wp);
    scan_kernel<<<1, 1024, 0, stream>>>(cnt, off);
    scatter_kernel<<<EE / 256, 256, 0, stream>>>(eidx, off, cur, csr);

    edge_mfma<<<EE / 128, 256, 0, stream>>>(hb, uvr, ea, be1, be2, bc1,
                                            wp, eidx, csr, agg, aggu, aggv);

    post_kernel<<<NLAT + (NN * LVN + 255) / 256, 256, 0, stream>>>(
        agg, latb, aggu, aggv, off);

    node_mfma<<<(NN + 127) / 128, 512, 0, stream>>>(hb, h, latb, bn1, bn2, wp, agg);
}